// Round 4
// baseline (3304.905 us; speedup 1.0000x reference)
//
#include <hip/hip_runtime.h>
#include <stdint.h>

// ---------------- problem constants ----------------
#define EMBD   256
#define HID    512
#define KTOT   768            // EMB + HID
#define NCLS   50257
#define STEPS  512

// ---------------- persistent-kernel partition ----------------
#define NGROUP 8               // batch groups
#define GB     8               // batches per group
#define BPG    32              // blocks per group (hidden split)
#define HS     16              // hidden units per block -> 64 gate rows
#define RP     129             // red tile pitch in floats (129 mod 32 = 1 -> conflict-free)

typedef float f32x4  __attribute__((ext_vector_type(4)));
typedef short bf16x8 __attribute__((ext_vector_type(8)));
typedef unsigned long long u64;

__device__ __forceinline__ unsigned bf16_rne(float f) {
  unsigned u = __float_as_uint(f);
  return (u + 0x7FFFu + ((u >> 16) & 1u)) >> 16;
}
__device__ __forceinline__ float bf16_to_f32(unsigned b) {
  return __uint_as_float(b << 16);
}

// ============ kernel 1: embedding gather + bf16 hi/lo pack ============
__global__ void emb_prep(const int* __restrict__ x, const float* __restrict__ emb,
                         unsigned* __restrict__ emb_hl) {
  int base = blockIdx.x * 4;
  int k = threadIdx.x;
  for (int it = 0; it < 4; ++it) {
    int tok = base + it;
    int id = x[tok];
    float w = emb[(size_t)id * EMBD + k];
    unsigned hb = bf16_rne(w);
    unsigned lb = bf16_rne(w - bf16_to_f32(hb));
    emb_hl[(size_t)tok * EMBD + k] = hb | (lb << 16);
  }
}

// ============ kernel 2: persistent LSTM recurrence ============
// 256 blocks (cooperative), 512 thr. group g = blockIdx&7 (same-XCD under rr
// dispatch -> exchange stays in that XCD's L2; perf-only assumption).
// NO LDS staging: MFMA A-fragments are loaded DIRECTLY from the tagged
// exchange buffer (lane m<8 reads 8 contiguous u64 {tag,hi|lo} per k-tile);
// tag==step check doubles as the synchronization poll. k-tiles per wave:
// 1 emb tile (no dependency, computed while h loads are in flight) + 2 h
// tiles (wait on only 4 producer blocks). One barrier per step (red is
// parity double-buffered).
__global__ __launch_bounds__(512, 2) void lstm_persist(
    const float* __restrict__ Ww, const float* __restrict__ Wb,
    const unsigned* __restrict__ emb_hl,
    u64* __restrict__ hbuf,
    unsigned short* __restrict__ h_hi, unsigned short* __restrict__ h_lo)
{
  __shared__ __align__(16) float red[2][32 * RP];

  const int tid  = threadIdx.x;
  const int wave = tid >> 6;
  const int lane = tid & 63;
  const int g = blockIdx.x & 7;     // batch group 0..7  (XCD-local under rr)
  const int s = blockIdx.x >> 3;    // hidden slice 0..31

  const int cn = lane & 15;         // A: batch row / B: gate-row col
  const int qk = (lane >> 4) * 8;   // k quarter offset
  const int mm = cn < 8 ? cn : 0;   // clamped batch for addressing
  const bool mvalid = cn < 8;

  // ---- k-tile assignment: wave w -> tiles {w (emb), 8+2w, 9+2w (h)} ----
  const int ktile[3] = { wave, 8 + 2 * wave, 9 + 2 * wave };
  const int u0 = wave * 64;         // first h unit of this wave's h tiles

  // ---- load W B-fragments into registers (one time) ----
  bf16x8 whi[3][4], wlo[3][4];
#pragma unroll
  for (int i = 0; i < 3; ++i) {
    int k0 = ktile[i] * 32 + qk;
#pragma unroll
    for (int nt = 0; nt < 4; ++nt) {
      int row = nt * 512 + s * HS + cn;
      const float* src = Ww + (size_t)row * KTOT + k0;
      float4 w0 = *(const float4*)src;
      float4 w1 = *(const float4*)(src + 4);
      float wv[8] = {w0.x, w0.y, w0.z, w0.w, w1.x, w1.y, w1.z, w1.w};
#pragma unroll
      for (int j = 0; j < 8; ++j) {
        unsigned hb = bf16_rne(wv[j]);
        unsigned lb = bf16_rne(wv[j] - bf16_to_f32(hb));
        whi[i][nt][j] = (short)hb;
        wlo[i][nt][j] = (short)lb;
      }
    }
  }

  const float bias = Wb[(lane >> 4) * 512 + s * HS + (lane & 15)];

  float Cst = 0.0f;  // cell state for (batch=wave, unit=lane) on lanes<16

  // emb A-frag source: batch g*8+mm, k slice = wave*32+qk, per-step stride EMBD
  const unsigned* embp0 =
      emb_hl + ((size_t)(g * GB + mm) * STEPS) * EMBD + wave * 32 + qk;
  u64* hg = hbuf + (size_t)g * 2 * GB * HID;

  for (int step = 0; step < STEPS; ++step) {
    // ---- fire h A-frag loads (tagged u64, L2-coherent within group) ----
    u64 v[16];
#pragma unroll
    for (int j = 0; j < 16; ++j) v[j] = 0;
    const u64* hp = hg + ((size_t)((step & 1) * GB + mm)) * HID + u0 + qk;
    if (mvalid) {
#pragma unroll
      for (int j = 0; j < 8; ++j) {
        v[j]     = __hip_atomic_load(&hp[j],      __ATOMIC_RELAXED,
                                     __HIP_MEMORY_SCOPE_AGENT);
        v[8 + j] = __hip_atomic_load(&hp[32 + j], __ATOMIC_RELAXED,
                                     __HIP_MEMORY_SCOPE_AGENT);
      }
    }

    // ---- emb A-frag load + 12 emb MFMAs (overlap the h-load latency) ----
    f32x4 acc[4] = {{0.f,0.f,0.f,0.f},{0.f,0.f,0.f,0.f},
                    {0.f,0.f,0.f,0.f},{0.f,0.f,0.f,0.f}};
    {
      bf16x8 ehi = {0,0,0,0,0,0,0,0}, elo = {0,0,0,0,0,0,0,0};
      if (mvalid) {
        const unsigned* ep = embp0 + (size_t)step * EMBD;
        uint4 a = *(const uint4*)ep;
        uint4 b = *(const uint4*)(ep + 4);
        unsigned w8[8] = {a.x, a.y, a.z, a.w, b.x, b.y, b.z, b.w};
#pragma unroll
        for (int j = 0; j < 8; ++j) {
          ehi[j] = (short)(w8[j] & 0xFFFFu);
          elo[j] = (short)(w8[j] >> 16);
        }
      }
#pragma unroll
      for (int nt = 0; nt < 4; ++nt) {
        acc[nt] = __builtin_amdgcn_mfma_f32_16x16x32_bf16(ehi, whi[0][nt], acc[nt], 0, 0, 0);
        acc[nt] = __builtin_amdgcn_mfma_f32_16x16x32_bf16(ehi, wlo[0][nt], acc[nt], 0, 0, 0);
        acc[nt] = __builtin_amdgcn_mfma_f32_16x16x32_bf16(elo, whi[0][nt], acc[nt], 0, 0, 0);
      }
    }

    // ---- tag check (the poll): retry until all 16 words carry tag==step ----
    if (mvalid) {
      const unsigned want = (unsigned)step;
      while (true) {
        bool ok = true;
#pragma unroll
        for (int j = 0; j < 16; ++j) ok &= ((unsigned)(v[j] >> 32) == want);
        if (ok) break;
#pragma unroll
        for (int j = 0; j < 8; ++j) {
          v[j]     = __hip_atomic_load(&hp[j],      __ATOMIC_RELAXED,
                                       __HIP_MEMORY_SCOPE_AGENT);
          v[8 + j] = __hip_atomic_load(&hp[32 + j], __ATOMIC_RELAXED,
                                       __HIP_MEMORY_SCOPE_AGENT);
        }
      }
    }

    // ---- unpack h frags + 24 h MFMAs ----
    {
      bf16x8 h1h, h1l, h2h, h2l;
#pragma unroll
      for (int j = 0; j < 8; ++j) {
        unsigned w32 = (unsigned)v[j];
        h1h[j] = (short)(w32 & 0xFFFFu);
        h1l[j] = (short)(w32 >> 16);
        w32 = (unsigned)v[8 + j];
        h2h[j] = (short)(w32 & 0xFFFFu);
        h2l[j] = (short)(w32 >> 16);
      }
#pragma unroll
      for (int nt = 0; nt < 4; ++nt) {
        acc[nt] = __builtin_amdgcn_mfma_f32_16x16x32_bf16(h1h, whi[1][nt], acc[nt], 0, 0, 0);
        acc[nt] = __builtin_amdgcn_mfma_f32_16x16x32_bf16(h1h, wlo[1][nt], acc[nt], 0, 0, 0);
        acc[nt] = __builtin_amdgcn_mfma_f32_16x16x32_bf16(h1l, whi[1][nt], acc[nt], 0, 0, 0);
        acc[nt] = __builtin_amdgcn_mfma_f32_16x16x32_bf16(h2h, whi[2][nt], acc[nt], 0, 0, 0);
        acc[nt] = __builtin_amdgcn_mfma_f32_16x16x32_bf16(h2h, wlo[2][nt], acc[nt], 0, 0, 0);
        acc[nt] = __builtin_amdgcn_mfma_f32_16x16x32_bf16(h2l, whi[2][nt], acc[nt], 0, 0, 0);
      }
    }

    // ---- k-split partials -> LDS (parity double-buffered) ----
    float* rp = red[step & 1];
    if (lane < 32) {
#pragma unroll
      for (int nt = 0; nt < 4; ++nt)
        *(f32x4*)&rp[(wave * 4 + nt) * RP + lane * 4] = acc[nt];
    }
    __syncthreads();   // the ONLY barrier per step

    // ---- reduction: thread owns (batch=wave, gate=lane>>4, unit=lane&15) ----
    float gsum = bias;
    {
      int tq = lane >> 4;
      int rbase = ((((wave >> 2) << 4) | (lane & 15)) << 2) + (wave & 3);
#pragma unroll
      for (int w = 0; w < 8; ++w)
        gsum += rp[(w * 4 + tq) * RP + rbase];
    }

    // ---- nonlinearities: lanes 0-15 f, 16-31 i, 32-47 o, 48-63 c~ ----
    float scl = (lane >= 48) ? 2.0f : 1.0f;
    float y = 1.0f / (1.0f + __expf(-gsum * scl));
    float act = (lane >= 48) ? (2.0f * y - 1.0f) : y;   // tanh via sigmoid
    float ig = __shfl(act, lane + 16);
    float og = __shfl(act, lane + 32);
    float cg = __shfl(act, lane + 48);
    if (lane < 16) {
      Cst = act * Cst + ig * cg;
      float t2 = 1.0f / (1.0f + __expf(-2.0f * Cst));
      float hv = og * (2.0f * t2 - 1.0f);
      unsigned hb = bf16_rne(hv);
      unsigned lb = bf16_rne(hv - bf16_to_f32(hb));
      u64 pack = ((u64)(unsigned)(step + 1) << 32) | (u64)(hb | (lb << 16));
      __hip_atomic_store(
          &hg[((size_t)((step + 1) & 1) * GB + wave) * HID + s * HS + lane],
          pack, __ATOMIC_RELAXED, __HIP_MEMORY_SCOPE_AGENT);
      if (step == STEPS - 1) {
        int m = g * GB + wave, k = s * HS + lane;
        h_hi[m * HID + k] = (unsigned short)hb;
        h_lo[m * HID + k] = (unsigned short)lb;
      }
    }
    // no trailing barrier: next iter writes red[other parity]; producers of
    // this parity's NEXT use are gated by the tag protocol (see proof above)
  }
}

// ============ kernel 3: out = h_final @ fcT + bias (MFMA hi/lo) ============
__device__ __forceinline__ void cvt8(const float4& a, const float4& b,
                                     bf16x8& hi, bf16x8& lo) {
  float v[8] = {a.x, a.y, a.z, a.w, b.x, b.y, b.z, b.w};
#pragma unroll
  for (int j = 0; j < 8; ++j) {
    unsigned hb = bf16_rne(v[j]);
    hi[j] = (short)hb;
    lo[j] = (short)bf16_rne(v[j] - bf16_to_f32(hb));
  }
}

__global__ __launch_bounds__(512) void fc_mfma(
    const unsigned short* __restrict__ h_hi, const unsigned short* __restrict__ h_lo,
    const float* __restrict__ fcw, const float* __restrict__ fcb,
    float* __restrict__ out)
{
  const int tid = threadIdx.x, wave = tid >> 6, lane = tid & 63;
  const int cn = lane & 15;
  const int qk = (lane >> 4) * 8;
  const int cls  = blockIdx.x * 128 + wave * 16 + cn;
  const int clsc = cls < NCLS ? cls : NCLS - 1;

  f32x4 acc[4] = {{0.f,0.f,0.f,0.f},{0.f,0.f,0.f,0.f},
                  {0.f,0.f,0.f,0.f},{0.f,0.f,0.f,0.f}};
#pragma unroll 2
  for (int kt = 0; kt < 16; ++kt) {
    int k0 = kt * 32 + qk;
    const float* bp = fcw + (size_t)clsc * HID + k0;
    float4 b0 = *(const float4*)bp;
    float4 b1 = *(const float4*)(bp + 4);
    bf16x8 bhi, blo;
    cvt8(b0, b1, bhi, blo);
#pragma unroll
    for (int mt = 0; mt < 4; ++mt) {
      bf16x8 ahi = *(const bf16x8*)&h_hi[(size_t)(mt * 16 + cn) * HID + k0];
      bf16x8 alo = *(const bf16x8*)&h_lo[(size_t)(mt * 16 + cn) * HID + k0];
      acc[mt] = __builtin_amdgcn_mfma_f32_16x16x32_bf16(ahi, bhi, acc[mt], 0, 0, 0);
      acc[mt] = __builtin_amdgcn_mfma_f32_16x16x32_bf16(ahi, blo, acc[mt], 0, 0, 0);
      acc[mt] = __builtin_amdgcn_mfma_f32_16x16x32_bf16(alo, bhi, acc[mt], 0, 0, 0);
    }
  }
  if (cls < NCLS) {
    float bias = fcb[cls];
#pragma unroll
    for (int mt = 0; mt < 4; ++mt)
#pragma unroll
      for (int j = 0; j < 4; ++j) {
        int m = mt * 16 + (lane >> 4) * 4 + j;
        out[(size_t)m * NCLS + cls] = acc[mt][j] + bias;
      }
  }
}

// ============ launcher ============
extern "C" void kernel_launch(void* const* d_in, const int* in_sizes, int n_in,
                              void* d_out, int out_size, void* d_ws, size_t ws_size,
                              hipStream_t stream) {
  const int*   x   = (const int*)d_in[0];
  const float* emb = (const float*)d_in[1];
  const float* Ww  = (const float*)d_in[2];
  const float* Wb  = (const float*)d_in[3];
  const float* fcw = (const float*)d_in[4];
  const float* fcb = (const float*)d_in[5];
  float* out = (float*)d_out;

  // workspace carve-up
  char* ws = (char*)d_ws;
  u64*            hbuf   = (u64*)ws;                          // 524,288 B
  unsigned short* h_hi   = (unsigned short*)(ws + 524288);    //  65,536 B
  unsigned short* h_lo   = (unsigned short*)(ws + 524288 + 65536);
  unsigned*       emb_hl = (unsigned*)(ws + 524288 + 131072); // 33.5 MB

  // zero h exchange buffer: tag=0 == "h for step 0 valid and zero"
  hipMemsetAsync(hbuf, 0, 524288, stream);

  emb_prep<<<8192, 256, 0, stream>>>(x, emb, emb_hl);

  void* args[] = { (void*)&Ww, (void*)&Wb, (void*)&emb_hl,
                   (void*)&hbuf, (void*)&h_hi, (void*)&h_lo };
  hipLaunchCooperativeKernel((void*)lstm_persist, dim3(256), dim3(512),
                             args, 0, stream);

  fc_mfma<<<(NCLS + 127) / 128, 512, 0, stream>>>(h_hi, h_lo, fcw, fcb, out);
}